// Round 2
// baseline (110.921 us; speedup 1.0000x reference)
//
#include <hip/hip_runtime.h>

#define NORB 96
#define NN 9216  // 96*96

// ---------------------------------------------------------------------------
// prep kernel: blocks 0..95  -> L = X @ H_core @ X^T (row i) + zero Km row i
//              blocks 96..191-> LayerNorm + QKV projection (row i)
// ---------------------------------------------------------------------------
__global__ __launch_bounds__(192) void prep_kernel(
    const float* __restrict__ X, const float* __restrict__ Hc,
    const float* __restrict__ x, const float* __restrict__ ln_s,
    const float* __restrict__ ln_b, const float* __restrict__ Wqkv,
    float* __restrict__ Lm, float* __restrict__ Km, float* __restrict__ qkv) {
  const int blk = blockIdx.x;
  const int t = threadIdx.x;  // 0..191
  if (blk < 96) {
    const int i = blk;
    __shared__ float Xs[NN];
    __shared__ float tmp[NORB];
    for (int f = t; f < NN; f += 192) Xs[f] = X[f];
    if (t < NORB) Km[i * NORB + t] = 0.f;
    __syncthreads();
    if (t < NORB) {
      // tmp[k] = sum_m X[i][m] * Hc[m][k]
      float acc = 0.f;
      for (int m = 0; m < NORB; ++m) acc += Xs[i * NORB + m] * Hc[m * NORB + t];
      tmp[t] = acc;
    }
    __syncthreads();
    if (t < NORB) {
      // L[i][j] = sum_k tmp[k] * X[j][k]
      float acc = 0.f;
      for (int k = 0; k < NORB; ++k) acc += tmp[k] * Xs[t * NORB + k];
      Lm[i * NORB + t] = acc;
    }
  } else {
    const int i = blk - 96;
    __shared__ float xn[128];
    __shared__ float red[3];
    float v = (t < 128) ? x[i * 128 + t] : 0.f;
    float s = v;
#pragma unroll
    for (int off = 32; off; off >>= 1) s += __shfl_down(s, off);
    if ((t & 63) == 0) red[t >> 6] = s;
    __syncthreads();
    const float mu = (red[0] + red[1] + red[2]) * (1.f / 128.f);
    __syncthreads();
    const float dv = (t < 128) ? (v - mu) : 0.f;
    s = dv * dv;
#pragma unroll
    for (int off = 32; off; off >>= 1) s += __shfl_down(s, off);
    if ((t & 63) == 0) red[t >> 6] = s;
    __syncthreads();
    const float var = (red[0] + red[1] + red[2]) * (1.f / 128.f);
    if (t < 128) xn[t] = dv * rsqrtf(var + 1e-6f) * ln_s[t] + ln_b[t];
    __syncthreads();
#pragma unroll
    for (int jj = 0; jj < 2; ++jj) {
      const int j = t + jj * 192;
      float acc = 0.f;
      for (int c = 0; c < 128; ++c) acc += xn[c] * Wqkv[c * 384 + j];
      qkv[i * 384 + j] = acc;
    }
  }
}

// ---------------------------------------------------------------------------
// Streaming J/K pass. Grid 1536 = 16 a-groups x 96 b. Block (g,b) streams
// slabs a = 6g..6g+5 (216 KB contiguous-per-slab), fully coalesced:
// wave-iter k reads float4 index t + 192k of the slab (3 KB/wave-instr).
// Thread (x=t%24, y=t/24) owns d = 4x..4x+3; c = y+8k.
//   J[a][b] = sum_{c,d} P[c][d]*eri  (block reduce per slab, direct write)
//   K[b][d] += sum_{a in grp, c} P[a][c]*eri (regs -> LDS -> 96 atomicAdds)
// ---------------------------------------------------------------------------
__global__ __launch_bounds__(192) void jk_kernel(
    const float* __restrict__ eri, const float* __restrict__ P,
    float* __restrict__ Jm, float* __restrict__ Km) {
  const int blk = blockIdx.x;
  const int g = blk & 15;
  const int b = blk >> 4;
  const int t = threadIdx.x;
  const int x = t % 24;
  const int y = t / 24;  // 0..7
  const float4* __restrict__ P4 = (const float4*)P;

  // P fragments: element f = c*24+x with c = y+8k  ->  f = t + 192k
  float4 pvr[12];
#pragma unroll
  for (int k = 0; k < 12; ++k) pvr[k] = P4[t + 192 * k];

  float k0 = 0.f, k1 = 0.f, k2 = 0.f, k3 = 0.f;
  __shared__ float klp[8][NORB];
  __shared__ float js[3];

  for (int s = 0; s < 6; ++s) {
    const int a = g * 6 + s;
    const float4* __restrict__ slab4 =
        (const float4*)(eri + (size_t)(a * NORB + b) * NN);
    float jp = 0.f;
#pragma unroll
    for (int k = 0; k < 12; ++k) {
      const float4 v = slab4[t + 192 * k];
      const float4 pv = pvr[k];
      const float pa = P[a * NORB + (y + 8 * k)];
      jp += v.x * pv.x + v.y * pv.y + v.z * pv.z + v.w * pv.w;
      k0 += pa * v.x;
      k1 += pa * v.y;
      k2 += pa * v.z;
      k3 += pa * v.w;
    }
#pragma unroll
    for (int off = 32; off; off >>= 1) jp += __shfl_down(jp, off);
    if ((t & 63) == 0) js[t >> 6] = jp;
    __syncthreads();
    if (t == 0) Jm[a * NORB + b] = js[0] + js[1] + js[2];
    __syncthreads();  // js reused next slab
  }

  klp[y][4 * x + 0] = k0;
  klp[y][4 * x + 1] = k1;
  klp[y][4 * x + 2] = k2;
  klp[y][4 * x + 3] = k3;
  __syncthreads();
  if (t < NORB) {
    float kk = 0.f;
#pragma unroll
    for (int yy = 0; yy < 8; ++yy) kk += klp[yy][t];
    atomicAdd(&Km[b * NORB + t], kk);
  }
}

// ---------------------------------------------------------------------------
// Biased multi-head attention. One block per (row i, head h) = 1536 blocks.
// ---------------------------------------------------------------------------
__global__ __launch_bounds__(128) void attn_kernel(
    const float* __restrict__ qkv, const float* __restrict__ Hc,
    const float* __restrict__ Jm, const float* __restrict__ Km,
    const float* __restrict__ Lm, float* __restrict__ aout) {
  const int i = blockIdx.x >> 4;
  const int h = blockIdx.x & 15;
  const int t = threadIdx.x;  // 0..127
  __shared__ float q_sh[8];
  __shared__ float p[NORB];
  __shared__ float redm[2];
  __shared__ float reds[2];
  __shared__ float pvred[16][8];

  if (t < 8) q_sh[t] = qkv[i * 384 + h * 8 + t];
  __syncthreads();

  float score = -1e30f;
  if (t < NORB) {
    const float* kr = qkv + t * 384 + 128 + h * 8;
    float d = 0.f;
#pragma unroll
    for (int dd = 0; dd < 8; ++dd) d += q_sh[dd] * kr[dd];
    d *= 0.3535533905932738f;  // 1/sqrt(8)
    const int ij = i * NORB + t;
    if (h < 2) d += Hc[ij];
    else if (h < 4) d += Jm[ij] - 0.5f * Km[ij];
    else if (h < 6) d += Lm[ij];
    score = d;
  }

  float m = score;
#pragma unroll
  for (int off = 32; off; off >>= 1) m = fmaxf(m, __shfl_down(m, off));
  if ((t & 63) == 0) redm[t >> 6] = m;
  __syncthreads();
  m = fmaxf(redm[0], redm[1]);

  float e = (t < NORB) ? __expf(score - m) : 0.f;
  float s = e;
#pragma unroll
  for (int off = 32; off; off >>= 1) s += __shfl_down(s, off);
  if ((t & 63) == 0) reds[t >> 6] = s;
  if (t < NORB) p[t] = e;
  __syncthreads();
  const float denom = reds[0] + reds[1];

  const int dd = t & 7;
  const int g = t >> 3;  // 0..15
  float acc = 0.f;
  for (int j = g; j < NORB; j += 16) acc += p[j] * qkv[j * 384 + 256 + h * 8 + dd];
  pvred[g][dd] = acc;
  __syncthreads();
  if (t < 8) {
    float o = 0.f;
#pragma unroll
    for (int g2 = 0; g2 < 16; ++g2) o += pvred[g2][t];
    aout[i * 128 + h * 8 + t] = o / denom;
  }
}

// ---------------------------------------------------------------------------
// Final projection: y[i][j] = bout[j] + sum_c aout[i][c] * Wout[c][j]
// ---------------------------------------------------------------------------
__global__ __launch_bounds__(128) void out_proj_kernel(
    const float* __restrict__ aout, const float* __restrict__ Wout,
    const float* __restrict__ bout, float* __restrict__ y) {
  const int i = blockIdx.x;
  const int j = threadIdx.x;  // 0..127
  __shared__ float row[128];
  row[j] = aout[i * 128 + j];
  __syncthreads();
  float acc = bout[j];
  for (int c = 0; c < 128; ++c) acc += row[c] * Wout[c * 128 + j];
  y[i * 128 + j] = acc;
}

// ---------------------------------------------------------------------------
extern "C" void kernel_launch(void* const* d_in, const int* in_sizes, int n_in,
                              void* d_out, int out_size, void* d_ws,
                              size_t ws_size, hipStream_t stream) {
  const float* x    = (const float*)d_in[0];
  const float* Hc   = (const float*)d_in[1];
  const float* X    = (const float*)d_in[2];
  const float* eri  = (const float*)d_in[3];
  const float* P    = (const float*)d_in[4];
  const float* ln_s = (const float*)d_in[5];
  const float* ln_b = (const float*)d_in[6];
  const float* Wqkv = (const float*)d_in[7];
  const float* Wout = (const float*)d_in[8];
  const float* bout = (const float*)d_in[9];
  float* y = (float*)d_out;

  float* ws   = (float*)d_ws;
  float* Jm   = ws;              // 9216
  float* Km   = ws + NN;         // 9216
  float* Lm   = ws + 2 * NN;     // 9216
  float* qkv  = ws + 3 * NN;     // 96*384
  float* aout = qkv + 96 * 384;  // 96*128

  // prep: L rows + Km zeroing (blocks 0-95), LN+QKV (blocks 96-191)
  prep_kernel<<<192, 192, 0, stream>>>(X, Hc, x, ln_s, ln_b, Wqkv, Lm, Km, qkv);

  // dominant pass: stream eri once (16 a-groups x 96 b), produce J and K
  jk_kernel<<<1536, 192, 0, stream>>>(eri, P, Jm, Km);

  // biased attention
  attn_kernel<<<NORB * 16, 128, 0, stream>>>(qkv, Hc, Jm, Km, Lm, aout);

  // output projection
  out_proj_kernel<<<NORB, 128, 0, stream>>>(aout, Wout, bout, y);
}

// Round 3
// 73.738 us; speedup vs baseline: 1.5043x; 1.5043x over previous
//
#include <hip/hip_runtime.h>

#define NORB 96
#define NN 9216  // 96*96

typedef float f32x4 __attribute__((ext_vector_type(4)));

// ---------------------------------------------------------------------------
// prep kernel: blocks 0..95  -> L = X @ H_core @ X^T (row i) + zero Km row i
//              blocks 96..191-> LayerNorm + QKV projection (row i)
// ---------------------------------------------------------------------------
__global__ __launch_bounds__(192) void prep_kernel(
    const float* __restrict__ X, const float* __restrict__ Hc,
    const float* __restrict__ x, const float* __restrict__ ln_s,
    const float* __restrict__ ln_b, const float* __restrict__ Wqkv,
    float* __restrict__ Lm, float* __restrict__ Km, float* __restrict__ qkv) {
  const int blk = blockIdx.x;
  const int t = threadIdx.x;  // 0..191
  if (blk < 96) {
    const int i = blk;
    __shared__ float Xs[NN];
    __shared__ float tmp[NORB];
    for (int f = t; f < NN; f += 192) Xs[f] = X[f];
    if (t < NORB) Km[i * NORB + t] = 0.f;
    __syncthreads();
    if (t < NORB) {
      float acc = 0.f;
      for (int m = 0; m < NORB; ++m) acc += Xs[i * NORB + m] * Hc[m * NORB + t];
      tmp[t] = acc;
    }
    __syncthreads();
    if (t < NORB) {
      float acc = 0.f;
      for (int k = 0; k < NORB; ++k) acc += tmp[k] * Xs[t * NORB + k];
      Lm[i * NORB + t] = acc;
    }
  } else {
    const int i = blk - 96;
    __shared__ float xn[128];
    __shared__ float red[3];
    float v = (t < 128) ? x[i * 128 + t] : 0.f;
    float s = v;
#pragma unroll
    for (int off = 32; off; off >>= 1) s += __shfl_down(s, off);
    if ((t & 63) == 0) red[t >> 6] = s;
    __syncthreads();
    const float mu = (red[0] + red[1] + red[2]) * (1.f / 128.f);
    __syncthreads();
    const float dv = (t < 128) ? (v - mu) : 0.f;
    s = dv * dv;
#pragma unroll
    for (int off = 32; off; off >>= 1) s += __shfl_down(s, off);
    if ((t & 63) == 0) red[t >> 6] = s;
    __syncthreads();
    const float var = (red[0] + red[1] + red[2]) * (1.f / 128.f);
    if (t < 128) xn[t] = dv * rsqrtf(var + 1e-6f) * ln_s[t] + ln_b[t];
    __syncthreads();
#pragma unroll
    for (int jj = 0; jj < 2; ++jj) {
      const int j = t + jj * 192;
      float acc = 0.f;
      for (int c = 0; c < 128; ++c) acc += xn[c] * Wqkv[c * 384 + j];
      qkv[i * 384 + j] = acc;
    }
  }
}

// ---------------------------------------------------------------------------
// Streaming J/K pass, one slab (a,b) per block, 384 threads (6 waves).
// Exactly ONE vmem instruction per 16B of eri (NT float4); pa from LDS,
// pv in 6 registers; NO barriers during the stream; J reduced once at end.
// Thread (x=t%24, y=t/24): owns d = 4x..4x+3, c = y + 16k (k=0..5).
//   float4 index f = c*24+x = t + 384k  -> coalesced 6KB per block-iter.
// ---------------------------------------------------------------------------
__global__ __launch_bounds__(384) void jk_kernel(
    const float* __restrict__ eri, const float* __restrict__ P,
    float* __restrict__ Jm, float* __restrict__ Km) {
  const int ab = blockIdx.x;
  const int a = ab / NORB;
  const int b = ab - a * NORB;
  const int t = threadIdx.x;
  const int x = t % 24;
  const int y = t / 24;  // 0..15
  const f32x4* __restrict__ slab4 = (const f32x4*)(eri + (size_t)ab * NN);
  const f32x4* __restrict__ P4 = (const f32x4*)P;

  __shared__ float pa_sh[NORB];
  __shared__ float klp[16][NORB];
  __shared__ float js[6];

  if (t < NORB) pa_sh[t] = P[a * NORB + t];

  f32x4 pvr[6];
#pragma unroll
  for (int k = 0; k < 6; ++k) pvr[k] = P4[t + 384 * k];
  __syncthreads();

  float jp = 0.f, k0 = 0.f, k1 = 0.f, k2 = 0.f, k3 = 0.f;
#pragma unroll
  for (int k = 0; k < 6; ++k) {
    const f32x4 v = __builtin_nontemporal_load(&slab4[t + 384 * k]);
    const float pa = pa_sh[y + 16 * k];
    jp += v.x * pvr[k].x + v.y * pvr[k].y + v.z * pvr[k].z + v.w * pvr[k].w;
    k0 += pa * v.x;
    k1 += pa * v.y;
    k2 += pa * v.z;
    k3 += pa * v.w;
  }

  klp[y][4 * x + 0] = k0;
  klp[y][4 * x + 1] = k1;
  klp[y][4 * x + 2] = k2;
  klp[y][4 * x + 3] = k3;
#pragma unroll
  for (int off = 32; off; off >>= 1) jp += __shfl_down(jp, off);
  if ((t & 63) == 0) js[t >> 6] = jp;
  __syncthreads();
  if (t == 0)
    Jm[ab] = js[0] + js[1] + js[2] + js[3] + js[4] + js[5];
  if (t < NORB) {
    float kk = 0.f;
#pragma unroll
    for (int yy = 0; yy < 16; ++yy) kk += klp[yy][t];
    atomicAdd(&Km[b * NORB + t], kk);
  }
}

// ---------------------------------------------------------------------------
// Biased multi-head attention. One block per (row i, head h) = 1536 blocks.
// ---------------------------------------------------------------------------
__global__ __launch_bounds__(128) void attn_kernel(
    const float* __restrict__ qkv, const float* __restrict__ Hc,
    const float* __restrict__ Jm, const float* __restrict__ Km,
    const float* __restrict__ Lm, float* __restrict__ aout) {
  const int i = blockIdx.x >> 4;
  const int h = blockIdx.x & 15;
  const int t = threadIdx.x;  // 0..127
  __shared__ float q_sh[8];
  __shared__ float p[NORB];
  __shared__ float redm[2];
  __shared__ float reds[2];
  __shared__ float pvred[16][8];

  if (t < 8) q_sh[t] = qkv[i * 384 + h * 8 + t];
  __syncthreads();

  float score = -1e30f;
  if (t < NORB) {
    const float* kr = qkv + t * 384 + 128 + h * 8;
    float d = 0.f;
#pragma unroll
    for (int dd = 0; dd < 8; ++dd) d += q_sh[dd] * kr[dd];
    d *= 0.3535533905932738f;  // 1/sqrt(8)
    const int ij = i * NORB + t;
    if (h < 2) d += Hc[ij];
    else if (h < 4) d += Jm[ij] - 0.5f * Km[ij];
    else if (h < 6) d += Lm[ij];
    score = d;
  }

  float m = score;
#pragma unroll
  for (int off = 32; off; off >>= 1) m = fmaxf(m, __shfl_down(m, off));
  if ((t & 63) == 0) redm[t >> 6] = m;
  __syncthreads();
  m = fmaxf(redm[0], redm[1]);

  float e = (t < NORB) ? __expf(score - m) : 0.f;
  float s = e;
#pragma unroll
  for (int off = 32; off; off >>= 1) s += __shfl_down(s, off);
  if ((t & 63) == 0) reds[t >> 6] = s;
  if (t < NORB) p[t] = e;
  __syncthreads();
  const float denom = reds[0] + reds[1];

  const int dd = t & 7;
  const int g = t >> 3;  // 0..15
  float acc = 0.f;
  for (int j = g; j < NORB; j += 16) acc += p[j] * qkv[j * 384 + 256 + h * 8 + dd];
  pvred[g][dd] = acc;
  __syncthreads();
  if (t < 8) {
    float o = 0.f;
#pragma unroll
    for (int g2 = 0; g2 < 16; ++g2) o += pvred[g2][t];
    aout[i * 128 + h * 8 + t] = o / denom;
  }
}

// ---------------------------------------------------------------------------
// Final projection: y[i][j] = bout[j] + sum_c aout[i][c] * Wout[c][j]
// ---------------------------------------------------------------------------
__global__ __launch_bounds__(128) void out_proj_kernel(
    const float* __restrict__ aout, const float* __restrict__ Wout,
    const float* __restrict__ bout, float* __restrict__ y) {
  const int i = blockIdx.x;
  const int j = threadIdx.x;  // 0..127
  __shared__ float row[128];
  row[j] = aout[i * 128 + j];
  __syncthreads();
  float acc = bout[j];
  for (int c = 0; c < 128; ++c) acc += row[c] * Wout[c * 128 + j];
  y[i * 128 + j] = acc;
}

// ---------------------------------------------------------------------------
extern "C" void kernel_launch(void* const* d_in, const int* in_sizes, int n_in,
                              void* d_out, int out_size, void* d_ws,
                              size_t ws_size, hipStream_t stream) {
  const float* x    = (const float*)d_in[0];
  const float* Hc   = (const float*)d_in[1];
  const float* X    = (const float*)d_in[2];
  const float* eri  = (const float*)d_in[3];
  const float* P    = (const float*)d_in[4];
  const float* ln_s = (const float*)d_in[5];
  const float* ln_b = (const float*)d_in[6];
  const float* Wqkv = (const float*)d_in[7];
  const float* Wout = (const float*)d_in[8];
  const float* bout = (const float*)d_in[9];
  float* y = (float*)d_out;

  float* ws   = (float*)d_ws;
  float* Jm   = ws;              // 9216
  float* Km   = ws + NN;         // 9216
  float* Lm   = ws + 2 * NN;     // 9216
  float* qkv  = ws + 3 * NN;     // 96*384
  float* aout = qkv + 96 * 384;  // 96*128

  // prep: L rows + Km zeroing (blocks 0-95), LN+QKV (blocks 96-191)
  prep_kernel<<<192, 192, 0, stream>>>(X, Hc, x, ln_s, ln_b, Wqkv, Lm, Km, qkv);

  // dominant pass: stream eri once (slab per block), produce J and K
  jk_kernel<<<NN, 384, 0, stream>>>(eri, P, Jm, Km);

  // biased attention
  attn_kernel<<<NORB * 16, 128, 0, stream>>>(qkv, Hc, Jm, Km, Lm, aout);

  // output projection
  out_proj_kernel<<<NORB, 128, 0, stream>>>(aout, Wout, bout, y);
}